// Round 1
// baseline (311.450 us; speedup 1.0000x reference)
//
#include <hip/hip_runtime.h>

// PatchTrainer: paint 100 filled circles (last-wins) over a 3x4096x4096 fp32 image.
// Per pixel: out = colors[max covering dot] else patch. Tile-culled, write-streaming.

#define IMG  4096
#define ND   100
#define TW   256   // tile width  (64 lanes x float4 = one full row per wave)
#define TH   64    // tile height (4 waves, 16 iterations of 4 rows)

__global__ __launch_bounds__(256) void patch_dots_kernel(
    const float* __restrict__ patch,    // [3][4096][4096]
    const float* __restrict__ centers,  // [100][2] (x, y)
    const float* __restrict__ radii,    // [100]
    const float* __restrict__ colors,   // [100][3]
    float* __restrict__ out)            // [3][4096][4096]
{
    __shared__ float s_xc[ND], s_yc[ND], s_r2[ND];
    __shared__ float s_c0[ND], s_c1[ND], s_c2[ND];
    __shared__ int   s_flag[ND];
    __shared__ int   s_list[ND];
    __shared__ int   s_cnt;

    const int tx0 = blockIdx.x * TW;
    const int ty0 = blockIdx.y * TH;
    const int t   = threadIdx.x;

    // Stage dot params in LDS + tile-intersection cull.
    if (t < ND) {
        // Bit-exact replication of the reference's fp32 math:
        float xc = floorf(centers[2 * t]     * 4096.0f);
        float yc = floorf(centers[2 * t + 1] * 4096.0f);
        float r  = floorf(radii[t] * (4096.0f / 5.0f));
        float r2 = r * r;
        s_xc[t] = xc; s_yc[t] = yc; s_r2[t] = r2;
        s_c0[t] = colors[3 * t];
        s_c1[t] = colors[3 * t + 1];
        s_c2[t] = colors[3 * t + 2];
        // Nearest pixel of this tile to the (integer-valued) center:
        float cx = fminf(fmaxf(xc, (float)tx0), (float)(tx0 + TW - 1));
        float cy = fminf(fmaxf(yc, (float)ty0), (float)(ty0 + TH - 1));
        float dx = xc - cx, dy = yc - cy;
        s_flag[t] = (dx * dx + dy * dy <= r2) ? 1 : 0;
    }
    __syncthreads();
    // Ordered compaction (preserves ascending dot index -> last-wins via overwrite).
    if (t == 0) {
        int c = 0;
        for (int i = 0; i < ND; ++i)
            if (s_flag[i]) s_list[c++] = i;
        s_cnt = c;
    }
    __syncthreads();
    const int cnt = s_cnt;

    const int lane = t & 63;
    const int w    = t >> 6;
    const int x0   = tx0 + lane * 4;
    const float fx0 = (float)x0;
    const float fx1 = (float)(x0 + 1);
    const float fx2 = (float)(x0 + 2);
    const float fx3 = (float)(x0 + 3);

    for (int it = 0; it < TH / 4; ++it) {
        const int   y  = ty0 + it * 4 + w;
        const float fy = (float)y;

        int b0 = -1, b1 = -1, b2 = -1, b3 = -1;
        for (int k = 0; k < cnt; ++k) {
            const int   i  = s_list[k];
            const float xc = s_xc[i];
            const float dy = fy - s_yc[i];
            // hit iff dx*dx <= r2 - dy*dy  (exact-integer fp32 region: equivalent
            // to dx*dx + dy*dy <= r2, which is the reference's comparison)
            const float t2 = s_r2[i] - dy * dy;
            float dx0 = fx0 - xc; if (dx0 * dx0 <= t2) b0 = i;
            float dx1 = fx1 - xc; if (dx1 * dx1 <= t2) b1 = i;
            float dx2 = fx2 - xc; if (dx2 * dx2 <= t2) b2 = i;
            float dx3 = fx3 - xc; if (dx3 * dx3 <= t2) b3 = i;
        }

        const size_t base = (size_t)y * IMG + x0;

        // Patch only needed where no dot covers (rare: ~1.5% of pixels).
        float4 p0 = make_float4(0.f, 0.f, 0.f, 0.f);
        float4 p1 = p0, p2 = p0;
        if ((b0 | b1 | b2 | b3) < 0) {   // any of the 4 pixels uncovered
            p0 = *(const float4*)(patch + base);
            p1 = *(const float4*)(patch + base + (size_t)IMG * IMG);
            p2 = *(const float4*)(patch + base + 2 * (size_t)IMG * IMG);
        }

        float4 o0, o1, o2;
        o0.x = (b0 >= 0) ? s_c0[b0] : p0.x;
        o0.y = (b1 >= 0) ? s_c0[b1] : p0.y;
        o0.z = (b2 >= 0) ? s_c0[b2] : p0.z;
        o0.w = (b3 >= 0) ? s_c0[b3] : p0.w;
        o1.x = (b0 >= 0) ? s_c1[b0] : p1.x;
        o1.y = (b1 >= 0) ? s_c1[b1] : p1.y;
        o1.z = (b2 >= 0) ? s_c1[b2] : p1.z;
        o1.w = (b3 >= 0) ? s_c1[b3] : p1.w;
        o2.x = (b0 >= 0) ? s_c2[b0] : p2.x;
        o2.y = (b1 >= 0) ? s_c2[b1] : p2.y;
        o2.z = (b2 >= 0) ? s_c2[b2] : p2.z;
        o2.w = (b3 >= 0) ? s_c2[b3] : p2.w;

        *(float4*)(out + base)                          = o0;
        *(float4*)(out + base + (size_t)IMG * IMG)      = o1;
        *(float4*)(out + base + 2 * (size_t)IMG * IMG)  = o2;
    }
}

extern "C" void kernel_launch(void* const* d_in, const int* in_sizes, int n_in,
                              void* d_out, int out_size, void* d_ws, size_t ws_size,
                              hipStream_t stream) {
    const float* patch   = (const float*)d_in[0];
    const float* centers = (const float*)d_in[1];
    const float* radii   = (const float*)d_in[2];
    const float* colors  = (const float*)d_in[3];
    float* out = (float*)d_out;

    dim3 grid(IMG / TW, IMG / TH);  // 16 x 64 = 1024 blocks
    dim3 block(256);
    patch_dots_kernel<<<grid, block, 0, stream>>>(patch, centers, radii, colors, out);
}

// Round 3
// 301.569 us; speedup vs baseline: 1.0328x; 1.0328x over previous
//
#include <hip/hip_runtime.h>

// PatchTrainer: paint 100 filled circles (last-wins) over a 3x4096x4096 fp32 image.
// Per pixel: out = colors[max covering dot] else patch. Tile-culled, write-streaming.
// R3: nontemporal stores via clang ext_vector_type (HIP float4 class rejected by builtin).

#define IMG  4096
#define ND   100
#define TW   256   // tile width  (64 lanes x float4 = one full row per wave)
#define TH   64    // tile height (4 waves, 16 iterations of 4 rows)

typedef float vfloat4 __attribute__((ext_vector_type(4)));  // builtin-compatible

__global__ __launch_bounds__(256) void patch_dots_kernel(
    const float* __restrict__ patch,    // [3][4096][4096]
    const float* __restrict__ centers,  // [100][2] (x, y)
    const float* __restrict__ radii,    // [100]
    const float* __restrict__ colors,   // [100][3]
    float* __restrict__ out)            // [3][4096][4096]
{
    __shared__ float  s_xc[ND], s_yc[ND], s_r2[ND];
    __shared__ float4 s_col[ND];
    __shared__ int    s_flag[ND];
    __shared__ int    s_list[ND];
    __shared__ int    s_cnt;

    const int tx0 = blockIdx.x * TW;
    const int ty0 = blockIdx.y * TH;
    const int t   = threadIdx.x;

    // Stage dot params in LDS + tile-intersection cull.
    if (t < ND) {
        // Bit-exact replication of the reference's fp32 math:
        float xc = floorf(centers[2 * t]     * 4096.0f);
        float yc = floorf(centers[2 * t + 1] * 4096.0f);
        float r  = floorf(radii[t] * (4096.0f / 5.0f));
        float r2 = r * r;
        s_xc[t] = xc; s_yc[t] = yc; s_r2[t] = r2;
        s_col[t] = make_float4(colors[3 * t], colors[3 * t + 1], colors[3 * t + 2], 0.f);
        // Nearest pixel of this tile to the (integer-valued) center:
        float cx = fminf(fmaxf(xc, (float)tx0), (float)(tx0 + TW - 1));
        float cy = fminf(fmaxf(yc, (float)ty0), (float)(ty0 + TH - 1));
        float dx = xc - cx, dy = yc - cy;
        s_flag[t] = (dx * dx + dy * dy <= r2) ? 1 : 0;
    }
    __syncthreads();
    // Ordered compaction (preserves ascending dot index -> last-wins via overwrite).
    if (t == 0) {
        int c = 0;
        for (int i = 0; i < ND; ++i)
            if (s_flag[i]) s_list[c++] = i;
        s_cnt = c;
    }
    __syncthreads();
    const int cnt = s_cnt;

    const int lane = t & 63;
    const int w    = t >> 6;
    const int x0   = tx0 + lane * 4;
    const float fx0 = (float)x0;
    const float fx1 = (float)(x0 + 1);
    const float fx2 = (float)(x0 + 2);
    const float fx3 = (float)(x0 + 3);

    for (int it = 0; it < TH / 4; ++it) {
        const int   y  = ty0 + it * 4 + w;
        const float fy = (float)y;

        int b0 = -1, b1 = -1, b2 = -1, b3 = -1;
        for (int k = 0; k < cnt; ++k) {
            const int   i  = s_list[k];
            const float xc = s_xc[i];
            const float dy = fy - s_yc[i];
            // hit iff dx*dx <= r2 - dy*dy  (exact-integer fp32 region: equivalent
            // to dx*dx + dy*dy <= r2, which is the reference's comparison)
            const float t2 = s_r2[i] - dy * dy;
            float dx0 = fx0 - xc; if (dx0 * dx0 <= t2) b0 = i;
            float dx1 = fx1 - xc; if (dx1 * dx1 <= t2) b1 = i;
            float dx2 = fx2 - xc; if (dx2 * dx2 <= t2) b2 = i;
            float dx3 = fx3 - xc; if (dx3 * dx3 <= t2) b3 = i;
        }

        const size_t base = (size_t)y * IMG + x0;

        // Patch only needed where no dot covers (rare: ~1.5% of pixels).
        float4 p0 = make_float4(0.f, 0.f, 0.f, 0.f);
        float4 p1 = p0, p2 = p0;
        if ((b0 | b1 | b2 | b3) < 0) {   // any of the 4 pixels uncovered
            p0 = *(const float4*)(patch + base);
            p1 = *(const float4*)(patch + base + (size_t)IMG * IMG);
            p2 = *(const float4*)(patch + base + 2 * (size_t)IMG * IMG);
        }

        // One ds_read_b128 per covered pixel instead of 3 ds_read_b32.
        const float4 c0 = (b0 >= 0) ? s_col[b0] : make_float4(p0.x, p1.x, p2.x, 0.f);
        const float4 c1 = (b1 >= 0) ? s_col[b1] : make_float4(p0.y, p1.y, p2.y, 0.f);
        const float4 c2 = (b2 >= 0) ? s_col[b2] : make_float4(p0.z, p1.z, p2.z, 0.f);
        const float4 c3 = (b3 >= 0) ? s_col[b3] : make_float4(p0.w, p1.w, p2.w, 0.f);

        vfloat4 o0, o1, o2;
        o0.x = c0.x; o0.y = c1.x; o0.z = c2.x; o0.w = c3.x;
        o1.x = c0.y; o1.y = c1.y; o1.z = c2.y; o1.w = c3.y;
        o2.x = c0.z; o2.y = c1.z; o2.z = c2.z; o2.w = c3.z;

        // Nontemporal: write-once stream, keep it out of L2.
        __builtin_nontemporal_store(o0, (vfloat4*)(out + base));
        __builtin_nontemporal_store(o1, (vfloat4*)(out + base + (size_t)IMG * IMG));
        __builtin_nontemporal_store(o2, (vfloat4*)(out + base + 2 * (size_t)IMG * IMG));
    }
}

extern "C" void kernel_launch(void* const* d_in, const int* in_sizes, int n_in,
                              void* d_out, int out_size, void* d_ws, size_t ws_size,
                              hipStream_t stream) {
    const float* patch   = (const float*)d_in[0];
    const float* centers = (const float*)d_in[1];
    const float* radii   = (const float*)d_in[2];
    const float* colors  = (const float*)d_in[3];
    float* out = (float*)d_out;

    dim3 grid(IMG / TW, IMG / TH);  // 16 x 64 = 1024 blocks
    dim3 block(256);
    patch_dots_kernel<<<grid, block, 0, stream>>>(patch, centers, radii, colors, out);
}